// Round 2
// baseline (27819.080 us; speedup 1.0000x reference)
//
#include <hip/hip_runtime.h>

// ManualLSTM on MI355X — fused-recurrence architecture (round 2).
// gates_t = [h_{t-1} ; e_t] @ [Wh | Wx]^T + bx   (K=512 f16 MFMA, f32 accum)
// 16 worker blocks = 4 batch-groups(16) x 4 h-chunks(64). Weights persistent in
// VGPRs (256/lane). Cross-block h exchange via agent-scope hbuf+flags (double
// buffered). ws use: 132 KB only (round-1 NaN diagnosed as ws overflow by the
// 131 MB lookup table corrupting the heap).

typedef _Float16 half8 __attribute__((ext_vector_type(8)));
typedef float f32x4 __attribute__((ext_vector_type(4)));

#define L2E 1.44269504088896340736f
#define T_STEPS 2048

__device__ __forceinline__ float fast_sigmoid(float x) {
  return __builtin_amdgcn_rcpf(1.f + __builtin_amdgcn_exp2f(-L2E * x));
}
__device__ __forceinline__ float fast_tanh(float x) {
  // 1 - 2/(exp(2x)+1); saturates to +/-1 for large |x|
  return 1.f - 2.f * __builtin_amdgcn_rcpf(1.f + __builtin_amdgcn_exp2f(2.f * L2E * x));
}

__global__ __launch_bounds__(256, 1) void lstm_rec(
    const int* __restrict__ x, const float* __restrict__ embed,
    const float* __restrict__ Wx, const float* __restrict__ bx,
    const float* __restrict__ Wh, float* __restrict__ hbuf,
    unsigned* __restrict__ flags, float* __restrict__ out) {
  // Same-XCD placement: workers are blockIdx % 8 == 0 (round-robin XCD map).
  if (blockIdx.x & 7) return;
  const int wid = blockIdx.x >> 3;  // worker 0..15
  const int bg = wid >> 2;          // batch group (16 batches)
  const int nc = wid & 3;           // h-chunk (64 cols)
  const int tid = threadIdx.x;
  const int lane = tid & 63;
  const int w = tid >> 6;           // wave id == gate id (i,f,g,o)
  const int j = tid & 63;
  const int eb = tid >> 4;          // e-gather: batch row 0..15
  const int seg = tid & 15;         // e-gather: 16-float segment
  const int ex = (eb & 7) << 4;     // row swizzle for eb

  __shared__ __align__(16) char Abuf[16 * 1024];  // [16 b][512 k] f16, rows XOR-swizzled
  __shared__ float gates[16 * 257];               // MFMA output staging (pad 257)
  __shared__ int tok[16][64];                     // upcoming tokens
  __shared__ int tok0[16];

  // ---- persistent fused weight fragments. Wave w = gate w, cols nc*64..+64.
  // k in [0,256) -> Wh row; k in [256,512) -> Wx row.
  half8 bfrag[4][16];
#pragma unroll
  for (int nt = 0; nt < 4; ++nt) {
    const int row = w * 256 + nc * 64 + nt * 16 + (lane & 15);
#pragma unroll
    for (int kk = 0; kk < 16; ++kk) {
      const float* p = (kk < 8)
          ? (Wh + (size_t)row * 256 + kk * 32 + ((lane >> 4) * 8))
          : (Wx + (size_t)row * 256 + (kk - 8) * 32 + ((lane >> 4) * 8));
      float4 u0 = *(const float4*)p;
      float4 u1 = *(const float4*)(p + 4);
      half8 hb = {(_Float16)u0.x, (_Float16)u0.y, (_Float16)u0.z, (_Float16)u0.w,
                  (_Float16)u1.x, (_Float16)u1.y, (_Float16)u1.z, (_Float16)u1.w};
      bfrag[nt][kk] = hb;
    }
  }

  float bxr[4];
#pragma unroll
  for (int g = 0; g < 4; ++g) bxr[g] = bx[g * 256 + nc * 64 + j];

  // ---- h_{-1} = 0 (zero the h region of Abuf)
  {
    half8 z = {(_Float16)0.f, (_Float16)0.f, (_Float16)0.f, (_Float16)0.f,
               (_Float16)0.f, (_Float16)0.f, (_Float16)0.f, (_Float16)0.f};
    int base = eb * 1024 + seg * 32;
    *(half8*)(Abuf + (base ^ ex)) = z;
    *(half8*)(Abuf + ((base + 16) ^ ex)) = z;
  }
  if (tid < 16) tok0[tid] = x[(size_t)(bg * 16 + tid) * 2048];
  __syncthreads();

  // ---- e_0 into Abuf k-region [256,512)
  {
    const float* ep = embed + (size_t)tok0[eb] * 256 + seg * 16;
    float4 e0 = ((const float4*)ep)[0], e1 = ((const float4*)ep)[1];
    float4 e2 = ((const float4*)ep)[2], e3 = ((const float4*)ep)[3];
    half8 h0 = {(_Float16)e0.x, (_Float16)e0.y, (_Float16)e0.z, (_Float16)e0.w,
                (_Float16)e1.x, (_Float16)e1.y, (_Float16)e1.z, (_Float16)e1.w};
    half8 h1 = {(_Float16)e2.x, (_Float16)e2.y, (_Float16)e2.z, (_Float16)e2.w,
                (_Float16)e3.x, (_Float16)e3.y, (_Float16)e3.z, (_Float16)e3.w};
    int base = eb * 1024 + 512 + seg * 32;
    *(half8*)(Abuf + (base ^ ex)) = h0;
    *(half8*)(Abuf + ((base + 16) ^ ex)) = h1;
  }
  __syncthreads();

  float c[4] = {0.f, 0.f, 0.f, 0.f};

  for (int t = 0; t < T_STEPS; ++t) {
    const bool tchunk = ((t & 63) == 0);
    const bool pf = (t < T_STEPS - 1);

    // ---- issue long-latency loads at loop top (latency hides under MFMA+cell)
    int tokreg[4];
    if (tchunk) {
#pragma unroll
      for (int u = 0; u < 4; ++u) {
        int id = tid + u * 256;
        int b = id >> 6, k = id & 63;
        int idx = t + 1 + k;
        if (idx > 2047) idx = 2047;
        tokreg[u] = x[(size_t)(bg * 16 + b) * 2048 + idx];
      }
    }
    float4 er0, er1, er2, er3;
    if (pf) {
      int etok = tchunk ? x[(size_t)(bg * 16 + eb) * 2048 + t + 1] : tok[eb][t & 63];
      const float* ep = embed + (size_t)etok * 256 + seg * 16;
      er0 = ((const float4*)ep)[0];
      er1 = ((const float4*)ep)[1];
      er2 = ((const float4*)ep)[2];
      er3 = ((const float4*)ep)[3];
    }

    // ---- phase A: gates = [h;e] @ Wslice^T  (4 col-tiles x K=512)
    f32x4 acc[4] = {{0.f, 0.f, 0.f, 0.f}, {0.f, 0.f, 0.f, 0.f},
                    {0.f, 0.f, 0.f, 0.f}, {0.f, 0.f, 0.f, 0.f}};
#pragma unroll
    for (int kk = 0; kk < 16; ++kk) {
      const int arow = lane & 15;
      half8 a = *(half8*)(Abuf +
          ((arow * 1024 + kk * 64 + ((lane >> 4) * 16)) ^ ((arow & 7) << 4)));
#pragma unroll
      for (int nt = 0; nt < 4; ++nt)
        acc[nt] = __builtin_amdgcn_mfma_f32_16x16x32_f16(a, bfrag[nt][kk], acc[nt], 0, 0, 0);
    }

    // ---- phase B: stage gate tiles to LDS (+ token chunk)
#pragma unroll
    for (int nt = 0; nt < 4; ++nt) {
#pragma unroll
      for (int jj = 0; jj < 4; ++jj) {
        int row = ((lane >> 4) << 2) + jj;  // D: row=(lane>>4)*4+reg, col=lane&15
        gates[row * 257 + w * 64 + nt * 16 + (lane & 15)] = acc[nt][jj];
      }
    }
    if (tchunk) {
#pragma unroll
      for (int u = 0; u < 4; ++u) {
        int id = tid + u * 256;
        tok[id >> 6][id & 63] = tokreg[u];
      }
    }
    __syncthreads();

    // ---- LSTM cell: 16 batches x 64 cols per block
#pragma unroll
    for (int k = 0; k < 4; ++k) {
      const int b = w + k * 4;
      float gi = gates[b * 257 + j] + bxr[0];
      float gf = gates[b * 257 + 64 + j] + bxr[1];
      float gg = gates[b * 257 + 128 + j] + bxr[2];
      float go = gates[b * 257 + 192 + j] + bxr[3];
      float iv = fast_sigmoid(gi);
      float fv = fast_sigmoid(gf);
      float gv = fast_tanh(gg);
      float ov = fast_sigmoid(go);
      c[k] = fv * c[k] + iv * gv;
      float hv = ov * fast_tanh(c[k]);
      if (t == T_STEPS - 1) {
        out[(size_t)(bg * 16 + b) * 256 + nc * 64 + j] = hv;
      } else {
        __hip_atomic_store(&hbuf[(t & 1) * 16384 + (bg * 16 + b) * 256 + nc * 64 + j],
                           hv, __ATOMIC_RELAXED, __HIP_MEMORY_SCOPE_AGENT);
        int off = (b * 1024 + (nc * 64 + j) * 2) ^ ((b & 7) << 4);
        *(_Float16*)(Abuf + off) = (_Float16)hv;
      }
    }
    if (t == T_STEPS - 1) break;

    __threadfence();   // drain hbuf stores (e-loads from loop top are long done)
    __syncthreads();   // all waves' stores drained before the publish

    if (tid == 0)
      __hip_atomic_store(&flags[wid * 16], (unsigned)(t + 1),
                         __ATOMIC_RELEASE, __HIP_MEMORY_SCOPE_AGENT);

    // ---- e_{t+1} -> Abuf (overlaps with the flag spin below)
    if (pf) {
      half8 h0 = {(_Float16)er0.x, (_Float16)er0.y, (_Float16)er0.z, (_Float16)er0.w,
                  (_Float16)er1.x, (_Float16)er1.y, (_Float16)er1.z, (_Float16)er1.w};
      half8 h1 = {(_Float16)er2.x, (_Float16)er2.y, (_Float16)er2.z, (_Float16)er2.w,
                  (_Float16)er3.x, (_Float16)er3.y, (_Float16)er3.z, (_Float16)er3.w};
      int base = eb * 1024 + 512 + seg * 32;
      *(half8*)(Abuf + (base ^ ex)) = h0;
      *(half8*)(Abuf + ((base + 16) ^ ex)) = h1;
    }

    // ---- wait for 3 peer chunks (acquire: L1 invalidated on success)
    if (w == 0 && lane < 3) {
      int pnc = lane + (lane >= nc ? 1 : 0);
      const unsigned* pflag = &flags[(bg * 4 + pnc) * 16];
      while (__hip_atomic_load(pflag, __ATOMIC_ACQUIRE, __HIP_MEMORY_SCOPE_AGENT) <
             (unsigned)(t + 1)) {
      }
    }
    __syncthreads();

    // ---- gather peer h chunks into Abuf
#pragma unroll
    for (int p = 0; p < 3; ++p) {
      const int pnc = p + (p >= nc ? 1 : 0);
#pragma unroll
      for (int k = 0; k < 4; ++k) {
        const int b = w + k * 4;
        float hv = __hip_atomic_load(
            &hbuf[(t & 1) * 16384 + (bg * 16 + b) * 256 + pnc * 64 + j],
            __ATOMIC_RELAXED, __HIP_MEMORY_SCOPE_AGENT);
        int off = (b * 1024 + (pnc * 64 + j) * 2) ^ ((b & 7) << 4);
        *(_Float16*)(Abuf + off) = (_Float16)hv;
      }
    }
    __syncthreads();
  }
}

// ---------------------------------------------------------------------------
extern "C" void kernel_launch(void* const* d_in, const int* in_sizes, int n_in,
                              void* d_out, int out_size, void* d_ws, size_t ws_size,
                              hipStream_t stream) {
  (void)in_sizes; (void)n_in; (void)out_size; (void)ws_size;
  const int* xx = (const int*)d_in[0];
  const float* embed = (const float*)d_in[1];
  const float* Wx = (const float*)d_in[2];
  const float* bx = (const float*)d_in[3];
  const float* Wh = (const float*)d_in[4];
  float* out = (float*)d_out;
  char* ws = (char*)d_ws;

  float* hbuf = (float*)ws;                    // 2*64*256*4 = 131072 B
  unsigned* flags = (unsigned*)(ws + 131072);  // 16*16*4    = 1024 B

  hipMemsetAsync(flags, 0, 1024, stream);
  lstm_rec<<<dim3(121), dim3(256), 0, stream>>>(xx, embed, Wx, bx, Wh, hbuf, flags, out);
}

// Round 3
// 7519.665 us; speedup vs baseline: 3.6995x; 3.6995x over previous
//
#include <hip/hip_runtime.h>

// ManualLSTM on MI355X — round 3: fence-free sentinel exchange.
// gates_t = [h_{t-1} ; e_t] @ [Wh | Wx]^T + bx  (K=512 f16 MFMA, f32 accum)
// 16 blocks = 4 batch-groups(16) x 4 h-chunks(64). Weights persistent in
// VGPR/AGPR. Cross-block h exchange: (tag|value) packed u64, RELAXED agent
// atomics only — no fences, no acquire (round-2's acquire-spin emitted
// buffer_inv per poll, nuking L2 -> 131 MB HBM refetch, 13.6 us/step).
// Per-block K layout permuted: [own h 0..63 | peers 64..255 | e 256..511]
// so the 3-phase MFMA split uses only static bfrag indices.

typedef _Float16 half8 __attribute__((ext_vector_type(8)));
typedef float f32x4 __attribute__((ext_vector_type(4)));
typedef unsigned long long u64;

#define L2E 1.44269504088896340736f
#define T_STEPS 2048

__device__ __forceinline__ float fast_sigmoid(float x) {
  return __builtin_amdgcn_rcpf(1.f + __builtin_amdgcn_exp2f(-L2E * x));
}
__device__ __forceinline__ float fast_tanh(float x) {
  return 1.f - 2.f * __builtin_amdgcn_rcpf(1.f + __builtin_amdgcn_exp2f(2.f * L2E * x));
}

__global__ __launch_bounds__(256, 1) void lstm_rec(
    const int* __restrict__ x, const float* __restrict__ embed,
    const float* __restrict__ Wx, const float* __restrict__ bx,
    const float* __restrict__ Wh, u64* __restrict__ hbuf,
    float* __restrict__ out) {
  const int tid = threadIdx.x;
  const int lane = tid & 63;
  const int w = tid >> 6;          // wave id == gate id (i,f,g,o)
  const int bg = blockIdx.x >> 2;  // batch group (16 batches)
  const int nc = blockIdx.x & 3;   // h-chunk (64 cols)
  const int j = lane;
  const int eb = tid >> 4;         // e-gather batch row
  const int seg = tid & 15;        // 16-float segment
  const int ex = (eb & 7) << 4;

  __shared__ __align__(16) char Abuf[16 * 1024];  // [16 b][512 k'] f16, XOR-swizzled
  __shared__ float gates[16 * 257];
  __shared__ int tok[16][64];
  __shared__ int tok0[16];

  // ---- persistent weights, permuted K: kk 0..1 own-h, 2..7 peers, 8..15 e.
  half8 bfrag[4][16];
#pragma unroll
  for (int nt = 0; nt < 4; ++nt) {
    const int row = w * 256 + nc * 64 + nt * 16 + (lane & 15);
#pragma unroll
    for (int kk = 0; kk < 16; ++kk) {
      const float* p;
      if (kk < 2) {
        p = Wh + (size_t)row * 256 + nc * 64 + kk * 32 + ((lane >> 4) * 8);
      } else if (kk < 8) {
        int pp = (kk - 2) >> 1, q = (kk - 2) & 1;
        int pnc = pp + (pp >= nc ? 1 : 0);
        p = Wh + (size_t)row * 256 + pnc * 64 + q * 32 + ((lane >> 4) * 8);
      } else {
        p = Wx + (size_t)row * 256 + (kk - 8) * 32 + ((lane >> 4) * 8);
      }
      float4 u0 = *(const float4*)p;
      float4 u1 = *(const float4*)(p + 4);
      half8 hb = {(_Float16)u0.x, (_Float16)u0.y, (_Float16)u0.z, (_Float16)u0.w,
                  (_Float16)u1.x, (_Float16)u1.y, (_Float16)u1.z, (_Float16)u1.w};
      bfrag[nt][kk] = hb;
    }
  }

  float bxr[4];
#pragma unroll
  for (int g = 0; g < 4; ++g) bxr[g] = bx[g * 256 + nc * 64 + j];

  // ---- h_{-1} = 0 (k' 0..255)
  {
    half8 z = {(_Float16)0.f, (_Float16)0.f, (_Float16)0.f, (_Float16)0.f,
               (_Float16)0.f, (_Float16)0.f, (_Float16)0.f, (_Float16)0.f};
    int base = eb * 1024 + seg * 32;
    *(half8*)(Abuf + (base ^ ex)) = z;
    *(half8*)(Abuf + ((base + 16) ^ ex)) = z;
  }
  if (tid < 16) tok0[tid] = x[(size_t)(bg * 16 + tid) * 2048];
  __syncthreads();

  // ---- e_0 into k' 256..511
  {
    const float* ep = embed + (size_t)tok0[eb] * 256 + seg * 16;
    float4 e0 = ((const float4*)ep)[0], e1 = ((const float4*)ep)[1];
    float4 e2 = ((const float4*)ep)[2], e3 = ((const float4*)ep)[3];
    half8 h0 = {(_Float16)e0.x, (_Float16)e0.y, (_Float16)e0.z, (_Float16)e0.w,
                (_Float16)e1.x, (_Float16)e1.y, (_Float16)e1.z, (_Float16)e1.w};
    half8 h1 = {(_Float16)e2.x, (_Float16)e2.y, (_Float16)e2.z, (_Float16)e2.w,
                (_Float16)e3.x, (_Float16)e3.y, (_Float16)e3.z, (_Float16)e3.w};
    int base = eb * 1024 + 512 + seg * 32;
    *(half8*)(Abuf + (base ^ ex)) = h0;
    *(half8*)(Abuf + ((base + 16) ^ ex)) = h1;
  }
  __syncthreads();

  float c[4] = {0.f, 0.f, 0.f, 0.f};

  for (int t = 0; t < T_STEPS; ++t) {
    const bool tchunk = ((t & 63) == 0);
    const bool pf = (t < T_STEPS - 1);
    const bool last = (t == T_STEPS - 1);

    // ---- issue long-latency loads first
    int tokreg[4];
    if (tchunk) {
#pragma unroll
      for (int u = 0; u < 4; ++u) {
        int id = tid + u * 256;
        int b = id >> 6, k = id & 63;
        int idx = t + 1 + k;
        if (idx > 2047) idx = 2047;
        tokreg[u] = x[(size_t)(bg * 16 + b) * 2048 + idx];
      }
    }
    float4 er0, er1, er2, er3;
    if (pf) {
      int etok = tchunk ? x[(size_t)(bg * 16 + eb) * 2048 + t + 1] : tok[eb][t & 63];
      const float* ep = embed + (size_t)etok * 256 + seg * 16;
      er0 = ((const float4*)ep)[0];
      er1 = ((const float4*)ep)[1];
      er2 = ((const float4*)ep)[2];
      er3 = ((const float4*)ep)[3];
    }

    // ---- first poll round issued early (hides under phase A+B MFMA)
    const unsigned want = (unsigned)t;  // h_{t-1} carries tag t
    const u64* hb = hbuf + (size_t)((t - 1) & 1) * 16384;
    u64 pv[12];
    if (t > 0) {
#pragma unroll
      for (int i = 0; i < 12; ++i) {
        int p = i >> 2, k = i & 3;
        int pnc = p + (p >= nc ? 1 : 0);
        int b = w + k * 4;
        pv[i] = __hip_atomic_load(&hb[(size_t)(bg * 16 + b) * 256 + pnc * 64 + j],
                                  __ATOMIC_RELAXED, __HIP_MEMORY_SCOPE_AGENT);
      }
    }

    f32x4 acc[4] = {{0.f, 0.f, 0.f, 0.f}, {0.f, 0.f, 0.f, 0.f},
                    {0.f, 0.f, 0.f, 0.f}, {0.f, 0.f, 0.f, 0.f}};
    const int arow = lane & 15;
    const int aswz = (arow & 7) << 4;

    // ---- phase A: e-part (kk 8..15)
#pragma unroll
    for (int kk = 8; kk < 16; ++kk) {
      half8 a = *(half8*)(Abuf + ((arow * 1024 + kk * 64 + ((lane >> 4) * 16)) ^ aswz));
#pragma unroll
      for (int nt = 0; nt < 4; ++nt)
        acc[nt] = __builtin_amdgcn_mfma_f32_16x16x32_f16(a, bfrag[nt][kk], acc[nt], 0, 0, 0);
    }
    // ---- phase B: own-h (kk 0..1)
#pragma unroll
    for (int kk = 0; kk < 2; ++kk) {
      half8 a = *(half8*)(Abuf + ((arow * 1024 + kk * 64 + ((lane >> 4) * 16)) ^ aswz));
#pragma unroll
      for (int nt = 0; nt < 4; ++nt)
        acc[nt] = __builtin_amdgcn_mfma_f32_16x16x32_f16(a, bfrag[nt][kk], acc[nt], 0, 0, 0);
    }

    // ---- phase C: consume peer h (tag-validated), retry until all 12 land
    if (t > 0) {
      bool ok[12];
      int rem = 12;
#pragma unroll
      for (int i = 0; i < 12; ++i) {
        ok[i] = ((unsigned)(pv[i] >> 32) >= want);
        if (ok[i]) {
          int p = i >> 2, k = i & 3;
          int b = w + k * 4;
          float hv = __uint_as_float((unsigned)pv[i]);
          int off = (b * 1024 + (64 + 64 * p + j) * 2) ^ ((b & 7) << 4);
          *(_Float16*)(Abuf + off) = (_Float16)hv;
          --rem;
        }
      }
      while (rem) {
#pragma unroll
        for (int i = 0; i < 12; ++i) {
          if (!ok[i]) {
            int p = i >> 2, k = i & 3;
            int pnc = p + (p >= nc ? 1 : 0);
            int b = w + k * 4;
            u64 v = __hip_atomic_load(&hb[(size_t)(bg * 16 + b) * 256 + pnc * 64 + j],
                                      __ATOMIC_RELAXED, __HIP_MEMORY_SCOPE_AGENT);
            if ((unsigned)(v >> 32) >= want) {
              float hv = __uint_as_float((unsigned)v);
              int off = (b * 1024 + (64 + 64 * p + j) * 2) ^ ((b & 7) << 4);
              *(_Float16*)(Abuf + off) = (_Float16)hv;
              ok[i] = true;
              --rem;
            }
          }
        }
      }
    }
    __syncthreads();

    // ---- phase D: peer-h (kk 2..7)
#pragma unroll
    for (int kk = 2; kk < 8; ++kk) {
      half8 a = *(half8*)(Abuf + ((arow * 1024 + kk * 64 + ((lane >> 4) * 16)) ^ aswz));
#pragma unroll
      for (int nt = 0; nt < 4; ++nt)
        acc[nt] = __builtin_amdgcn_mfma_f32_16x16x32_f16(a, bfrag[nt][kk], acc[nt], 0, 0, 0);
    }

    // ---- stage gate tiles (+ token chunk)
#pragma unroll
    for (int nt = 0; nt < 4; ++nt) {
#pragma unroll
      for (int jj = 0; jj < 4; ++jj) {
        int row = ((lane >> 4) << 2) + jj;
        gates[row * 257 + w * 64 + nt * 16 + (lane & 15)] = acc[nt][jj];
      }
    }
    if (tchunk) {
#pragma unroll
      for (int u = 0; u < 4; ++u) {
        int id = tid + u * 256;
        tok[id >> 6][id & 63] = tokreg[u];
      }
    }
    __syncthreads();

    // ---- LSTM cell (16 batches x 64 cols), publish h_t
    u64* pub = hbuf + (size_t)(t & 1) * 16384;
#pragma unroll
    for (int k = 0; k < 4; ++k) {
      const int b = w + k * 4;
      float gi = gates[b * 257 + j] + bxr[0];
      float gf = gates[b * 257 + 64 + j] + bxr[1];
      float gg = gates[b * 257 + 128 + j] + bxr[2];
      float go = gates[b * 257 + 192 + j] + bxr[3];
      float iv = fast_sigmoid(gi);
      float fv = fast_sigmoid(gf);
      float gv = fast_tanh(gg);
      float ov = fast_sigmoid(go);
      c[k] = fv * c[k] + iv * gv;
      float hv = ov * fast_tanh(c[k]);
      if (last) {
        out[(size_t)(bg * 16 + b) * 256 + nc * 64 + j] = hv;
      } else {
        u64 u = ((u64)(unsigned)(t + 1) << 32) | (u64)__float_as_uint(hv);
        __hip_atomic_store(&pub[(size_t)(bg * 16 + b) * 256 + nc * 64 + j], u,
                           __ATOMIC_RELAXED, __HIP_MEMORY_SCOPE_AGENT);
        int off = (b * 1024 + j * 2) ^ ((b & 7) << 4);
        *(_Float16*)(Abuf + off) = (_Float16)hv;
      }
    }
    if (last) break;

    // ---- e_{t+1} -> Abuf (reads of e_t finished in phase A, pre-barrier-1)
    {
      half8 h0 = {(_Float16)er0.x, (_Float16)er0.y, (_Float16)er0.z, (_Float16)er0.w,
                  (_Float16)er1.x, (_Float16)er1.y, (_Float16)er1.z, (_Float16)er1.w};
      half8 h1 = {(_Float16)er2.x, (_Float16)er2.y, (_Float16)er2.z, (_Float16)er2.w,
                  (_Float16)er3.x, (_Float16)er3.y, (_Float16)er3.z, (_Float16)er3.w};
      int base = eb * 1024 + 512 + seg * 32;
      *(half8*)(Abuf + (base ^ ex)) = h0;
      *(half8*)(Abuf + ((base + 16) ^ ex)) = h1;
    }
    __syncthreads();
  }
}

// ---------------------------------------------------------------------------
extern "C" void kernel_launch(void* const* d_in, const int* in_sizes, int n_in,
                              void* d_out, int out_size, void* d_ws, size_t ws_size,
                              hipStream_t stream) {
  (void)in_sizes; (void)n_in; (void)out_size; (void)ws_size;
  const int* xx = (const int*)d_in[0];
  const float* embed = (const float*)d_in[1];
  const float* Wx = (const float*)d_in[2];
  const float* bx = (const float*)d_in[3];
  const float* Wh = (const float*)d_in[4];
  float* out = (float*)d_out;

  u64* hbuf = (u64*)d_ws;  // 2 slots x 64 batches x 256 cols x 8 B = 262144 B

  hipMemsetAsync(hbuf, 0, 262144, stream);  // tags must start < 1
  lstm_rec<<<dim3(16), dim3(256), 0, stream>>>(xx, embed, Wx, bx, Wh, hbuf, out);
}